// Round 4
// baseline (50.553 us; speedup 1.0000x reference)
//
#include <hip/hip_runtime.h>
#include <stdint.h>

// ---------------- problem constants ----------------
#define B_ROWS 16384
#define LATD   128
#define HIDD   1024
#define ZSTR   140      // u16 stride for 64-row LDS tiles (70 dwords -> conflict-light)

typedef __bf16 bf16x8 __attribute__((ext_vector_type(8)));
typedef float  f32x4  __attribute__((ext_vector_type(4)));
typedef float  f32x4v __attribute__((ext_vector_type(4)));   // for nontemporal builtins
typedef unsigned short ushort8v __attribute__((ext_vector_type(8)));

// barrier that does NOT drain vmcnt (keeps weight prefetches in flight)
#define WG_BARRIER() do {                                          \
    asm volatile("s_waitcnt lgkmcnt(0)" ::: "memory");             \
    __builtin_amdgcn_s_barrier();                                  \
    asm volatile("" ::: "memory");                                 \
  } while (0)

// ---------------- threefry2x32 (matches JAX, partitionable default) ----------------
struct TF2 { unsigned int a, b; };

#define TF_R(x0,x1,r) { x0 += x1; x1 = ((x1 << (r)) | (x1 >> (32 - (r)))); x1 ^= x0; }

__host__ __device__ constexpr TF2 threefry2x32(unsigned k0, unsigned k1, unsigned c0, unsigned c1) {
  unsigned ks2 = k0 ^ k1 ^ 0x1BD11BDAu;
  unsigned x0 = c0 + k0, x1 = c1 + k1;
  TF_R(x0,x1,13) TF_R(x0,x1,15) TF_R(x0,x1,26) TF_R(x0,x1,6)
  x0 += k1;  x1 += ks2 + 1u;
  TF_R(x0,x1,17) TF_R(x0,x1,29) TF_R(x0,x1,16) TF_R(x0,x1,24)
  x0 += ks2; x1 += k0 + 2u;
  TF_R(x0,x1,13) TF_R(x0,x1,15) TF_R(x0,x1,26) TF_R(x0,x1,6)
  x0 += k0;  x1 += k1 + 3u;
  TF_R(x0,x1,17) TF_R(x0,x1,29) TF_R(x0,x1,16) TF_R(x0,x1,24)
  x0 += k1;  x1 += ks2 + 4u;
  TF_R(x0,x1,13) TF_R(x0,x1,15) TF_R(x0,x1,26) TF_R(x0,x1,6)
  x0 += ks2; x1 += k0 + 5u;
  return {x0, x1};
}

constexpr TF2 NK0 = threefry2x32(0u, 1u, 0u, 0u);  // bin heads
constexpr TF2 NK1 = threefry2x32(0u, 1u, 0u, 1u);  // like heads
constexpr TF2 NK2 = threefry2x32(0u, 1u, 0u, 2u);  // mask heads

__device__ __forceinline__ unsigned short f2bf(float f) {
  unsigned u = __float_as_uint(f);
  return (unsigned short)((u + 0x7fffu + ((u >> 16) & 1u)) >> 16);
}

// ---------------- prep: fragment-linear packed bf16 weights in d_ws ----------------
__global__ void prep_kernel(const float* __restrict__ W1,
                            const float* __restrict__ Wnum, const float* __restrict__ Wcat,
                            const float* __restrict__ Wbin, const float* __restrict__ Wlike,
                            const float* __restrict__ Wmask,
                            const float* __restrict__ bnum, const float* __restrict__ bcat,
                            const float* __restrict__ bbin, const float* __restrict__ blike,
                            const float* __restrict__ bmask,
                            unsigned short* __restrict__ W1p,
                            unsigned short* __restrict__ Wallp,
                            float* __restrict__ ball) {
  int t = blockIdx.x * 256 + threadIdx.x;
  if (t < 16384) {                         // W1p: frag f = nt*4+ks; elem: n=(f>>2)*16+(l&15), k=(f&3)*32+(l>>4)*8+j
    int f = t >> 6, l = t & 63;
    int n = (f >> 2) * 16 + (l & 15);
    int kk0 = (f & 3) * 32 + (l >> 4) * 8;
    ushort8v p;
    #pragma unroll
    for (int j = 0; j < 8; ++j) p[j] = f2bf(W1[(size_t)(kk0 + j) * HIDD + n]);
    *(ushort8v*)(W1p + (size_t)t * 8) = p;
  } else if (t < 16384 + 40960) {          // Wallp: frag g = nt*32+kt
    int t2 = t - 16384;
    int g = t2 >> 6, l = t2 & 63;
    int nt = g >> 5, kt = g & 31;
    int n = nt * 16 + (l & 15);
    int kk0 = kt * 32 + (l >> 4) * 8;
    ushort8v p;
    #pragma unroll
    for (int j = 0; j < 8; ++j) {
      int kk = kk0 + j;
      float v = 0.f;
      if (n < 32)       v = Wnum [(size_t)kk * 32  + n];
      else if (n < 230) v = Wcat [(size_t)kk * 198 + (n - 32)];
      else if (n < 238) v = Wbin [(size_t)kk * 8   + (n - 230)];
      else if (n < 240) v = Wlike[(size_t)kk * 2   + (n - 238)];
      else if (n < 294) v = Wmask[(size_t)kk * 54  + (n - 240)];
      p[j] = f2bf(v);
    }
    *(ushort8v*)(Wallp + (size_t)t2 * 8) = p;
  } else if (t < 16384 + 40960 + 320) {    // ball
    int n = t - (16384 + 40960);
    float v = 0.f;
    if (n < 32)       v = bnum [n];
    else if (n < 230) v = bcat [n - 32];
    else if (n < 238) v = bbin [n - 230];
    else if (n < 240) v = blike[n - 238];
    else if (n < 294) v = bmask[n - 240];
    ball[n] = v;
  }
}

// ---------------- main fused decoder ----------------
// 256 WGs x 512 threads (8 waves). WG owns 64 rows.
// wave = (wk, wc): wk = chunk-half {0,1}, wc = col quarter (80 out cols).
// LDS: zs[64][140] + H[2][2][64][140] bf16 (5 x 17920 B = 89600); reused as outs[64][321] f32.
// Schedule per chunk i: issue wb2(i) -> GEMM1(i) -> pack->H[wk][i&1] -> prefetch wb1(i+1)
//                       -> barrier (lgkm only, vmcnt stays in flight) -> GEMM2(i).
__global__ __launch_bounds__(512, 2) void decoder_kernel(
    const float* __restrict__ z, const float* __restrict__ b1,
    const unsigned short* __restrict__ W1p, const unsigned short* __restrict__ Wallp,
    const float* __restrict__ ball, float* __restrict__ out) {
  __shared__ __align__(16) unsigned char smem[89600];
  unsigned short* zs = (unsigned short*)smem;                 // [64][140]
  float* outs = (float*)smem;                                 // [64][321]

  const int tid  = threadIdx.x;
  const int lane = tid & 63;
  const int wv   = tid >> 6;        // 0..7
  const int wc   = wv & 3;          // col quarter
  const int wk   = wv >> 2;         // chunk half
  const int l15  = lane & 15;
  const int l4   = lane >> 4;
  const int r0   = blockIdx.x * 64;

  unsigned short* H0 = (unsigned short*)(smem + 17920 + wk * 35840);
  unsigned short* H1 = H0 + 8960;

  // ---- stage z tile -> LDS bf16 (nontemporal reads: streamed once) ----
  #pragma unroll
  for (int it = 0; it < 2; ++it) {
    int ch  = tid + it * 512;       // 0..1023
    int row = ch >> 4;
    int k0  = (ch & 15) * 8;
    const float* src = z + (size_t)(r0 + row) * LATD + k0;
    f32x4v f0 = __builtin_nontemporal_load((const f32x4v*)src);
    f32x4v f1 = __builtin_nontemporal_load((const f32x4v*)(src + 4));
    ushort8v p;
    p[0] = f2bf(f0[0]); p[1] = f2bf(f0[1]); p[2] = f2bf(f0[2]); p[3] = f2bf(f0[3]);
    p[4] = f2bf(f1[0]); p[5] = f2bf(f1[1]); p[6] = f2bf(f1[2]); p[7] = f2bf(f1[3]);
    *(ushort8v*)(zs + row * ZSTR + k0) = p;
  }

  // ---- biases for GEMM1 (tiny, L2) ----
  float bb[4][2];
  #pragma unroll
  for (int i = 0; i < 4; ++i)
    #pragma unroll
    for (int ct = 0; ct < 2; ++ct)
      bb[i][ct] = b1[(wk * 4 + i) * 128 + wc * 32 + ct * 16 + l15];

  // ---- prefetch wb1 for chunk 0 (stays in flight across the barrier) ----
  bf16x8 wb1[2][4];
  {
    const int c0 = wk * 4;
    #pragma unroll
    for (int ct = 0; ct < 2; ++ct)
      #pragma unroll
      for (int ks = 0; ks < 4; ++ks)
        wb1[ct][ks] = *(const bf16x8*)(W1p + (size_t)(((c0 * 8 + wc * 2 + ct) * 4 + ks) * 64 + lane) * 8);
  }

  f32x4 acc2[4][5] = {};

  WG_BARRIER();   // zs visible; weight prefetch NOT drained

  #pragma unroll
  for (int i = 0; i < 4; ++i) {
    const int c = wk * 4 + i;
    // ---- issue second-GEMM weights now; consumed after pack+barrier ----
    bf16x8 wb2[5][4];
    #pragma unroll
    for (int ct = 0; ct < 5; ++ct)
      #pragma unroll
      for (int ks = 0; ks < 4; ++ks)
        wb2[ct][ks] = *(const bf16x8*)(Wallp + (size_t)(((wc * 5 + ct) * 32 + c * 4 + ks) * 64 + lane) * 8);

    // ---- first GEMM: h[64][32 cols @ wc] ----
    f32x4 acc1[4][2] = {};
    #pragma unroll
    for (int ks = 0; ks < 4; ++ks) {
      bf16x8 za[4];
      #pragma unroll
      for (int rt = 0; rt < 4; ++rt)
        za[rt] = *(const bf16x8*)(zs + (rt * 16 + l15) * ZSTR + ks * 32 + l4 * 8);
      #pragma unroll
      for (int rt = 0; rt < 4; ++rt)
        #pragma unroll
        for (int ct = 0; ct < 2; ++ct)
          acc1[rt][ct] = __builtin_amdgcn_mfma_f32_16x16x32_bf16(za[rt], wb1[ct][ks], acc1[rt][ct], 0, 0, 0);
    }

    // ---- pack h -> H[wk][i&1] (WAR safe: previous barrier ordered GEMM2(i-2)) ----
    unsigned short* hw = (i & 1) ? H1 : H0;
    #pragma unroll
    for (int rt = 0; rt < 4; ++rt)
      #pragma unroll
      for (int ct = 0; ct < 2; ++ct)
        #pragma unroll
        for (int j = 0; j < 4; ++j) {
          float v = fmaxf(acc1[rt][ct][j] + bb[i][ct], 0.f);
          hw[(rt * 16 + l4 * 4 + j) * ZSTR + wc * 32 + ct * 16 + l15] = f2bf(v);
        }

    // ---- prefetch next chunk's wb1 (latency hides under barrier + GEMM2) ----
    if (i < 3) {
      const int cn = c + 1;
      #pragma unroll
      for (int ct = 0; ct < 2; ++ct)
        #pragma unroll
        for (int ks = 0; ks < 4; ++ks)
          wb1[ct][ks] = *(const bf16x8*)(W1p + (size_t)(((cn * 8 + wc * 2 + ct) * 4 + ks) * 64 + lane) * 8);
    }

    WG_BARRIER();   // pack visible; vmcnt prefetches stay in flight

    // ---- second GEMM: acc2 += h_chunk @ Wall[chunk, wc-cols] ----
    #pragma unroll
    for (int ks = 0; ks < 4; ++ks) {
      bf16x8 ha[4];
      #pragma unroll
      for (int rt = 0; rt < 4; ++rt)
        ha[rt] = *(const bf16x8*)(hw + (rt * 16 + l15) * ZSTR + ks * 32 + l4 * 8);
      #pragma unroll
      for (int rt = 0; rt < 4; ++rt)
        #pragma unroll
        for (int ct = 0; ct < 5; ++ct)
          acc2[rt][ct] = __builtin_amdgcn_mfma_f32_16x16x32_bf16(ha[rt], wb2[ct][ks], acc2[rt][ct], 0, 0, 0);
    }
  }

  __syncthreads();   // all LDS reads done; reuse as outs

  // ---- 2-way wk reduction into outs[64][321] ----
  float bias2[5];
  #pragma unroll
  for (int ct = 0; ct < 5; ++ct) bias2[ct] = ball[wc * 80 + ct * 16 + l15];

  if (wk == 0) {
    #pragma unroll
    for (int rt = 0; rt < 4; ++rt)
      #pragma unroll
      for (int ct = 0; ct < 5; ++ct)
        #pragma unroll
        for (int j = 0; j < 4; ++j)
          outs[(rt * 16 + l4 * 4 + j) * 321 + wc * 80 + ct * 16 + l15] = acc2[rt][ct][j] + bias2[ct];
  }
  __syncthreads();
  if (wk == 1) {
    #pragma unroll
    for (int rt = 0; rt < 4; ++rt)
      #pragma unroll
      for (int ct = 0; ct < 5; ++ct)
        #pragma unroll
        for (int j = 0; j < 4; ++j)
          outs[(rt * 16 + l4 * 4 + j) * 321 + wc * 80 + ct * 16 + l15] += acc2[rt][ct][j];
  }
  __syncthreads();

  // ---- write num + cat blocks (row-major [B, card] chunks, contiguous float4, NT) ----
  {
    constexpr int cards[13] = {32,10,20,15,8,30,12,5,25,6,40,18,9};
    constexpr int cbase[13] = {0,32,42,62,77,85,115,127,132,157,163,203,221};
    #pragma unroll
    for (int blk = 0; blk < 13; ++blk) {
      const int card = cards[blk];
      const int cb   = cbase[blk];
      float* gout = out + (size_t)B_ROWS * cb + (size_t)r0 * card;
      for (int v = tid; v < card * 16; v += 512) {
        int g = v * 4;
        f32x4v vbuf;
        #pragma unroll
        for (int e = 0; e < 4; ++e) {
          int ge = g + e;
          int brow = ge / card;          // compile-time card -> magic mul
          int j = ge - brow * card;
          vbuf[e] = outs[brow * 321 + cb + j];
        }
        __builtin_nontemporal_store(vbuf, (f32x4v*)(gout + g));
      }
    }
  }

  // ---- gumbel-sigmoid heads: cols 230..293, out[B*c + b] ----
  {
    int c = 230 + (tid >> 3);
    unsigned ka, kb; int Nh, head;
    if (c < 238)      { ka = NK0.a; kb = NK0.b; Nh = 8;  head = c - 230; }
    else if (c < 240) { ka = NK1.a; kb = NK1.b; Nh = 2;  head = c - 238; }
    else              { ka = NK2.a; kb = NK2.b; Nh = 54; head = c - 240; }
    #pragma unroll
    for (int q = 0; q < 2; ++q) {
      int rb = (tid & 7) * 4 + q * 32;
      f32x4v vbuf;
      #pragma unroll
      for (int e = 0; e < 4; ++e) {
        int rl = rb + e;
        float x = outs[rl * 321 + c];
        unsigned j = (unsigned)((r0 + rl) * Nh + head);
        TF2 t = threefry2x32(ka, kb, 0u, j);
        unsigned bits = t.a ^ t.b;
        float u  = __uint_as_float((bits >> 9) | 0x3f800000u) - 1.0f;
        float gn = -logf(-logf(u + 1e-20f) + 1e-20f);
        vbuf[e] = 1.0f / (1.0f + expf(-(x + gn)));
      }
      __builtin_nontemporal_store(vbuf, (f32x4v*)(out + (size_t)B_ROWS * c + r0 + rb));
    }
  }
}

// ---------------- launch ----------------
extern "C" void kernel_launch(void* const* d_in, const int* in_sizes, int n_in,
                              void* d_out, int out_size, void* d_ws, size_t ws_size,
                              hipStream_t stream) {
  const float* z     = (const float*)d_in[0];
  const float* W1    = (const float*)d_in[1];
  const float* b1    = (const float*)d_in[2];
  const float* Wnum  = (const float*)d_in[3];
  const float* bnum  = (const float*)d_in[4];
  const float* Wcat  = (const float*)d_in[5];
  const float* bcat  = (const float*)d_in[6];
  const float* Wbin  = (const float*)d_in[7];
  const float* bbin  = (const float*)d_in[8];
  const float* Wlike = (const float*)d_in[9];
  const float* blike = (const float*)d_in[10];
  const float* Wmask = (const float*)d_in[11];
  const float* bmask = (const float*)d_in[12];

  unsigned short* W1p   = (unsigned short*)d_ws;            // 131072 bf16
  unsigned short* Wallp = W1p + 131072;                     // 327680 bf16
  float*          ball  = (float*)(Wallp + 327680);         // 320 f32

  const int total = 16384 + 40960 + 320;
  prep_kernel<<<(total + 255) / 256, 256, 0, stream>>>(
      W1, Wnum, Wcat, Wbin, Wlike, Wmask, bnum, bcat, bbin, blike, bmask,
      W1p, Wallp, ball);

  decoder_kernel<<<B_ROWS / 64, 512, 0, stream>>>(
      z, b1, W1p, Wallp, ball, (float*)d_out);
}